// Round 1
// baseline (687.025 us; speedup 1.0000x reference)
//
#include <hip/hip_runtime.h>

#define NNODES 100000
#define NEDGES 600000
#define HDIM   128
#define H2     256
#define ROWS   16

// ---------------------------------------------------------------------------
// Scatter-sum: one thread per (edge, channel). sums[node][c] += edge_attr[e][c]
// cnt[node] += 1 (channel-0 lane only).
// ---------------------------------------------------------------------------
__global__ __launch_bounds__(256) void scatter_kernel(
    const float* __restrict__ edge_attr,
    const int*   __restrict__ col,
    float*       __restrict__ sums,
    float*       __restrict__ cnt)
{
    int idx = blockIdx.x * 256 + threadIdx.x;          // < 76.8M, fits int32
    if (idx >= NEDGES * HDIM) return;
    int e = idx >> 7;                                  // edge id
    int c = idx & (HDIM - 1);                          // channel
    int node = col[e];
    atomicAdd(&sums[node * HDIM + c], edge_attr[idx]);
    if (c == 0) atomicAdd(&cnt[node], 1.0f);
}

// ---------------------------------------------------------------------------
// Fused: agg = sums/max(cnt,1); h = [x, agg] @ W1 + b1; LayerNorm; PReLU;
// out = h @ W2 + b2.  One block = 16 rows, 256 threads.
// ---------------------------------------------------------------------------
__global__ __launch_bounds__(256) void fused_kernel(
    const float* __restrict__ x,
    const float* __restrict__ sums,
    const float* __restrict__ cnt,
    const float* __restrict__ W1,
    const float* __restrict__ b1,
    const float* __restrict__ gamma,
    const float* __restrict__ beta,
    const float* __restrict__ prelu_a,
    const float* __restrict__ W2,
    const float* __restrict__ b2,
    float*       __restrict__ out)
{
    __shared__ float hbuf[ROWS][H2];   // 16 KB, reused: h_in then h_mid

    const int t    = threadIdx.x;      // 0..255
    const int row0 = blockIdx.x * ROWS;

    // ---- Phase 1: build h_in = [x | agg] rows in LDS --------------------
    for (int r = 0; r < ROWS; ++r) {
        int row = row0 + r;
        float v;
        if (t < HDIM) {
            v = x[(size_t)row * HDIM + t];
        } else {
            float c = cnt[row];
            v = sums[(size_t)row * HDIM + (t - HDIM)] / fmaxf(c, 1.0f);
        }
        hbuf[r][t] = v;
    }
    __syncthreads();

    // ---- Phase 2: GEMM1 — thread t owns output column j=t for 16 rows ---
    float acc[ROWS];
#pragma unroll
    for (int r = 0; r < ROWS; ++r) acc[r] = 0.0f;

    for (int k = 0; k < H2; k += 4) {
        float w0 = W1[(k + 0) * H2 + t];
        float w1 = W1[(k + 1) * H2 + t];
        float w2 = W1[(k + 2) * H2 + t];
        float w3 = W1[(k + 3) * H2 + t];
#pragma unroll
        for (int r = 0; r < ROWS; ++r) {
            float4 hv = *(const float4*)&hbuf[r][k];   // wave-broadcast read
            acc[r] = fmaf(hv.x, w0, acc[r]);
            acc[r] = fmaf(hv.y, w1, acc[r]);
            acc[r] = fmaf(hv.z, w2, acc[r]);
            acc[r] = fmaf(hv.w, w3, acc[r]);
        }
    }
    float bb1 = b1[t];
    __syncthreads();                    // done reading h_in
#pragma unroll
    for (int r = 0; r < ROWS; ++r) hbuf[r][t] = acc[r] + bb1;
    __syncthreads();

    // ---- Phase 3: LayerNorm + PReLU, wave w handles rows 4w..4w+3 -------
    const int wave = t >> 6, lane = t & 63;
    const float aP = prelu_a[0];
    const float g0 = gamma[lane],       g1 = gamma[lane + 64];
    const float g2 = gamma[lane + 128], g3 = gamma[lane + 192];
    const float e0 = beta[lane],        e1 = beta[lane + 64];
    const float e2 = beta[lane + 128],  e3 = beta[lane + 192];

    for (int rr = 0; rr < 4; ++rr) {
        int r = wave * 4 + rr;
        float v0 = hbuf[r][lane];
        float v1 = hbuf[r][lane + 64];
        float v2 = hbuf[r][lane + 128];
        float v3 = hbuf[r][lane + 192];
        float s  = v0 + v1 + v2 + v3;
        float sq = v0 * v0 + v1 * v1 + v2 * v2 + v3 * v3;
#pragma unroll
        for (int off = 32; off; off >>= 1) {
            s  += __shfl_xor(s,  off, 64);
            sq += __shfl_xor(sq, off, 64);
        }
        float mu   = s * (1.0f / H2);
        float var  = sq * (1.0f / H2) - mu * mu;
        float rsig = rsqrtf(var + 1e-5f);

        float n0 = (v0 - mu) * rsig * g0 + e0;
        float n1 = (v1 - mu) * rsig * g1 + e1;
        float n2 = (v2 - mu) * rsig * g2 + e2;
        float n3 = (v3 - mu) * rsig * g3 + e3;
        n0 = n0 >= 0.0f ? n0 : aP * n0;
        n1 = n1 >= 0.0f ? n1 : aP * n1;
        n2 = n2 >= 0.0f ? n2 : aP * n2;
        n3 = n3 >= 0.0f ? n3 : aP * n3;
        hbuf[r][lane]       = n0;
        hbuf[r][lane + 64]  = n1;
        hbuf[r][lane + 128] = n2;
        hbuf[r][lane + 192] = n3;
    }
    __syncthreads();

    // ---- Phase 4: GEMM2 — thread t: column j2 = t&127, rows g*8..g*8+7 --
    const int j2 = t & (HDIM - 1);
    const int g  = t >> 7;              // 0 or 1
    float acc2[8];
#pragma unroll
    for (int r = 0; r < 8; ++r) acc2[r] = 0.0f;

    for (int k = 0; k < H2; k += 4) {
        float w0 = W2[(k + 0) * HDIM + j2];
        float w1 = W2[(k + 1) * HDIM + j2];
        float w2 = W2[(k + 2) * HDIM + j2];
        float w3 = W2[(k + 3) * HDIM + j2];
#pragma unroll
        for (int r = 0; r < 8; ++r) {
            float4 hv = *(const float4*)&hbuf[g * 8 + r][k];
            acc2[r] = fmaf(hv.x, w0, acc2[r]);
            acc2[r] = fmaf(hv.y, w1, acc2[r]);
            acc2[r] = fmaf(hv.z, w2, acc2[r]);
            acc2[r] = fmaf(hv.w, w3, acc2[r]);
        }
    }
    float bb2 = b2[j2];
#pragma unroll
    for (int r = 0; r < 8; ++r) {
        out[(size_t)(row0 + g * 8 + r) * HDIM + j2] = acc2[r] + bb2;
    }
}

// ---------------------------------------------------------------------------
extern "C" void kernel_launch(void* const* d_in, const int* in_sizes, int n_in,
                              void* d_out, int out_size, void* d_ws, size_t ws_size,
                              hipStream_t stream)
{
    const float* x        = (const float*)d_in[0];
    const int*   ei       = (const int*)  d_in[1];
    const float* edge_attr= (const float*)d_in[2];
    const float* W1       = (const float*)d_in[3];
    const float* b1       = (const float*)d_in[4];
    const float* gamma    = (const float*)d_in[5];
    const float* beta     = (const float*)d_in[6];
    const float* prelu_a  = (const float*)d_in[7];
    const float* W2       = (const float*)d_in[8];
    const float* b2       = (const float*)d_in[9];
    float*       out      = (float*)d_out;

    float* sums = (float*)d_ws;                       // [NNODES * HDIM]
    float* cnt  = sums + (size_t)NNODES * HDIM;       // [NNODES]

    hipMemsetAsync(d_ws, 0,
                   ((size_t)NNODES * HDIM + NNODES) * sizeof(float), stream);

    const int* colp = ei + NEDGES;                    // edge_index[1]

    scatter_kernel<<<(NEDGES * HDIM) / 256, 256, 0, stream>>>(
        edge_attr, colp, sums, cnt);

    fused_kernel<<<NNODES / ROWS, 256, 0, stream>>>(
        x, sums, cnt, W1, b1, gamma, beta, prelu_a, W2, b2, out);
}

// Round 2
// 463.959 us; speedup vs baseline: 1.4808x; 1.4808x over previous
//
#include <hip/hip_runtime.h>

#define NNODES 100000
#define NEDGES 600000
#define HDIM   128
#define H2     256

typedef __attribute__((ext_vector_type(8))) short short8;
typedef __attribute__((ext_vector_type(4))) float f32x4;

static __device__ __forceinline__ ushort f32_to_bf16(float f) {
    union { float f; uint u; } c; c.f = f;
    uint u = c.u;
    return (ushort)((u + 0x7fffu + ((u >> 16) & 1u)) >> 16);
}

// ---------------------------------------------------------------------------
// Scatter-sum (unchanged from R0): one thread per (edge, channel).
// ---------------------------------------------------------------------------
__global__ __launch_bounds__(256) void scatter_kernel(
    const float* __restrict__ edge_attr,
    const int*   __restrict__ col,
    float*       __restrict__ sums,
    float*       __restrict__ cnt)
{
    int idx = blockIdx.x * 256 + threadIdx.x;
    if (idx >= NEDGES * HDIM) return;
    int e = idx >> 7;
    int c = idx & (HDIM - 1);
    int node = col[e];
    atomicAdd(&sums[node * HDIM + c], edge_attr[idx]);
    if (c == 0) atomicAdd(&cnt[node], 1.0f);
}

// ---------------------------------------------------------------------------
// Pack W [K][ncols] f32 row-major -> bf16 MFMA B-frag order:
// Wp[((nt*8 + ks)*64 + lane)*8 + j] = bf16(W[ks*32 + (lane>>4)*8 + j][nt*16 + (lane&15)])
// ---------------------------------------------------------------------------
__global__ __launch_bounds__(256) void pack_w(
    const float* __restrict__ W, ushort* __restrict__ Wp, int ncols, int total)
{
    int id = blockIdx.x * 256 + threadIdx.x;
    if (id >= total) return;
    int l  = id & 63;
    int ks = (id >> 6) & 7;
    int nt = id >> 9;
    int colc = nt * 16 + (l & 15);
    int kb   = ks * 32 + (l >> 4) * 8;
    short8 v;
#pragma unroll
    for (int j = 0; j < 8; ++j)
        v[j] = (short)f32_to_bf16(W[(size_t)(kb + j) * ncols + colc]);
    *(short8*)&Wp[(size_t)id * 8] = v;
}

// ---------------------------------------------------------------------------
// Fused MFMA kernel: 64 rows/block, 256 threads (4 waves).
// agg-build -> GEMM1(bf16 mfma) -> bias -> LN -> PReLU -> GEMM2 -> out
// h tile in LDS, bf16, XOR-swizzled ((row&7)<<3 on ushort index).
// ---------------------------------------------------------------------------
__global__ __launch_bounds__(256) void fused_mfma(
    const float*  __restrict__ x,
    const float*  __restrict__ sums,
    const float*  __restrict__ cnt,
    const ushort* __restrict__ W1p,
    const float*  __restrict__ b1,
    const float*  __restrict__ gamma,
    const float*  __restrict__ beta,
    const float*  __restrict__ prelu_a,
    const ushort* __restrict__ W2p,
    const float*  __restrict__ b2,
    float*        __restrict__ out)
{
    __shared__ ushort hbuf[64 * 256];   // 32 KB bf16 tile (h_in, then h_mid)
    __shared__ float red_s[4][64];
    __shared__ float red_q[4][64];
    __shared__ float mu_l[64];
    __shared__ float rs_l[64];

    const int t = threadIdx.x;
    const int w = t >> 6;          // wave id
    const int l = t & 63;          // lane
    const int lrow = l & 15;       // row-in-tile (A) / col-in-tile (B,C)
    const int lk   = l >> 4;       // k sub-block / C row group
    const int row0 = blockIdx.x * 64;

    // ---- Phase 1: build h_in = [x | agg] bf16 tile (swizzled) -----------
    {
        const int sub = t >> 6;    // row offset within group of 4
        const int q   = t & 63;    // float4 slot within 256-col row
        for (int it = 0; it < 16; ++it) {
            int lr = it * 4 + sub;
            int row = row0 + lr; if (row >= NNODES) row = NNODES - 1;
            float4 v;
            if (q < 32) {
                v = *(const float4*)&x[(size_t)row * HDIM + q * 4];
            } else {
                v = *(const float4*)&sums[(size_t)row * HDIM + (q - 32) * 4];
                float inv = 1.0f / fmaxf(cnt[row], 1.0f);
                v.x *= inv; v.y *= inv; v.z *= inv; v.w *= inv;
            }
            uint idx = (((uint)lr << 8) + (uint)(q * 4)) ^ (((uint)lr & 7u) << 3);
            ushort4 hv;
            hv.x = f32_to_bf16(v.x); hv.y = f32_to_bf16(v.y);
            hv.z = f32_to_bf16(v.z); hv.w = f32_to_bf16(v.w);
            *(ushort4*)&hbuf[idx] = hv;
        }
    }
    __syncthreads();

    // ---- Phase 2: GEMM1 — wave w owns cols [w*64, w*64+64) ---------------
    f32x4 acc[4][4];
#pragma unroll
    for (int i = 0; i < 4; ++i)
#pragma unroll
        for (int j = 0; j < 4; ++j) acc[i][j] = (f32x4)(0.0f);

#pragma unroll
    for (int ks = 0; ks < 8; ++ks) {
        short8 a[4];
#pragma unroll
        for (int rt = 0; rt < 4; ++rt) {
            uint row = (uint)(rt * 16 + lrow);
            uint idx = ((row << 8) + (uint)(ks * 32 + lk * 8)) ^ ((row & 7u) << 3);
            a[rt] = *(const short8*)&hbuf[idx];
        }
#pragma unroll
        for (int ct = 0; ct < 4; ++ct) {
            short8 b = *(const short8*)&W1p[(size_t)(((w * 4 + ct) * 8 + ks) * 64 + l) * 8];
#pragma unroll
            for (int rt = 0; rt < 4; ++rt)
                acc[rt][ct] = __builtin_amdgcn_mfma_f32_16x16x32_bf16(
                    a[rt], b, acc[rt][ct], 0, 0, 0);
        }
    }

    // ---- Phase 3: +bias, LN partial sums (quarter-wave shfl), stats ------
    float b1c[4], g1c[4], be1c[4];
#pragma unroll
    for (int ct = 0; ct < 4; ++ct) {
        int colc = w * 64 + ct * 16 + lrow;
        b1c[ct] = b1[colc]; g1c[ct] = gamma[colc]; be1c[ct] = beta[colc];
    }
#pragma unroll
    for (int rt = 0; rt < 4; ++rt)
#pragma unroll
        for (int ct = 0; ct < 4; ++ct)
#pragma unroll
            for (int r = 0; r < 4; ++r) acc[rt][ct][r] += b1c[ct];

#pragma unroll
    for (int rt = 0; rt < 4; ++rt) {
        float s[4], qq[4];
#pragma unroll
        for (int r = 0; r < 4; ++r) {
            float v0 = acc[rt][0][r], v1 = acc[rt][1][r];
            float v2 = acc[rt][2][r], v3 = acc[rt][3][r];
            s[r]  = v0 + v1 + v2 + v3;
            qq[r] = v0*v0 + v1*v1 + v2*v2 + v3*v3;
        }
#pragma unroll
        for (int off = 1; off < 16; off <<= 1) {
#pragma unroll
            for (int r = 0; r < 4; ++r) {
                s[r]  += __shfl_xor(s[r],  off, 64);
                qq[r] += __shfl_xor(qq[r], off, 64);
            }
        }
        if (lrow == 0) {
#pragma unroll
            for (int r = 0; r < 4; ++r) {
                int row = rt * 16 + lk * 4 + r;
                red_s[w][row] = s[r];
                red_q[w][row] = qq[r];
            }
        }
    }
    __syncthreads();
    if (t < 64) {
        float s  = red_s[0][t] + red_s[1][t] + red_s[2][t] + red_s[3][t];
        float qq = red_q[0][t] + red_q[1][t] + red_q[2][t] + red_q[3][t];
        float mu  = s * (1.0f / H2);
        float var = qq * (1.0f / H2) - mu * mu;
        mu_l[t] = mu;
        rs_l[t] = rsqrtf(var + 1e-5f);
    }
    const float ap = prelu_a[0];
    __syncthreads();

    // ---- Phase 3b: normalize + PReLU -> h_mid bf16 (same LDS, swizzled) --
#pragma unroll
    for (int rt = 0; rt < 4; ++rt) {
#pragma unroll
        for (int r = 0; r < 4; ++r) {
            uint row = (uint)(rt * 16 + lk * 4 + r);
            float mu = mu_l[row], rs = rs_l[row];
#pragma unroll
            for (int ct = 0; ct < 4; ++ct) {
                uint colc = (uint)(w * 64 + ct * 16 + lrow);
                float v = (acc[rt][ct][r] - mu) * rs * g1c[ct] + be1c[ct];
                v = v >= 0.0f ? v : ap * v;
                uint idx = ((row << 8) + colc) ^ ((row & 7u) << 3);
                hbuf[idx] = f32_to_bf16(v);
            }
        }
    }
    __syncthreads();

    // ---- Phase 4: GEMM2 — wave w owns cols [w*32, w*32+32) ---------------
    f32x4 acc2[4][2];
#pragma unroll
    for (int i = 0; i < 4; ++i)
#pragma unroll
        for (int j = 0; j < 2; ++j) acc2[i][j] = (f32x4)(0.0f);

#pragma unroll
    for (int ks = 0; ks < 8; ++ks) {
        short8 a[4];
#pragma unroll
        for (int rt = 0; rt < 4; ++rt) {
            uint row = (uint)(rt * 16 + lrow);
            uint idx = ((row << 8) + (uint)(ks * 32 + lk * 8)) ^ ((row & 7u) << 3);
            a[rt] = *(const short8*)&hbuf[idx];
        }
#pragma unroll
        for (int ct = 0; ct < 2; ++ct) {
            short8 b = *(const short8*)&W2p[(size_t)(((w * 2 + ct) * 8 + ks) * 64 + l) * 8];
#pragma unroll
            for (int rt = 0; rt < 4; ++rt)
                acc2[rt][ct] = __builtin_amdgcn_mfma_f32_16x16x32_bf16(
                    a[rt], b, acc2[rt][ct], 0, 0, 0);
        }
    }

    float b2c[2];
#pragma unroll
    for (int ct = 0; ct < 2; ++ct) b2c[ct] = b2[w * 32 + ct * 16 + lrow];

#pragma unroll
    for (int rt = 0; rt < 4; ++rt)
#pragma unroll
        for (int ct = 0; ct < 2; ++ct)
#pragma unroll
            for (int r = 0; r < 4; ++r) {
                int row = row0 + rt * 16 + lk * 4 + r;
                if (row < NNODES)
                    out[(size_t)row * HDIM + w * 32 + ct * 16 + lrow] =
                        acc2[rt][ct][r] + b2c[ct];
            }
}

// ---------------------------------------------------------------------------
extern "C" void kernel_launch(void* const* d_in, const int* in_sizes, int n_in,
                              void* d_out, int out_size, void* d_ws, size_t ws_size,
                              hipStream_t stream)
{
    const float* x         = (const float*)d_in[0];
    const int*   ei        = (const int*)  d_in[1];
    const float* edge_attr = (const float*)d_in[2];
    const float* W1        = (const float*)d_in[3];
    const float* b1        = (const float*)d_in[4];
    const float* gamma     = (const float*)d_in[5];
    const float* beta      = (const float*)d_in[6];
    const float* prelu_a   = (const float*)d_in[7];
    const float* W2        = (const float*)d_in[8];
    const float* b2        = (const float*)d_in[9];
    float*       out       = (float*)d_out;

    float*  sums = (float*)d_ws;                          // [NNODES*HDIM]
    float*  cnt  = sums + (size_t)NNODES * HDIM;          // [NNODES]
    ushort* W1p  = (ushort*)(cnt + NNODES);               // 16*8*64*8 = 64K elems
    ushort* W2p  = W1p + 16 * 8 * 64 * 8;                 // 8*8*64*8 = 32K elems

    hipMemsetAsync(d_ws, 0,
                   ((size_t)NNODES * HDIM + NNODES) * sizeof(float), stream);

    pack_w<<<32, 256, 0, stream>>>(W1, W1p, H2,   16 * 8 * 64);
    pack_w<<<16, 256, 0, stream>>>(W2, W2p, HDIM,  8 * 8 * 64);

    const int* colp = ei + NEDGES;
    scatter_kernel<<<(NEDGES * HDIM) / 256, 256, 0, stream>>>(
        edge_attr, colp, sums, cnt);

    fused_mfma<<<(NNODES + 63) / 64, 256, 0, stream>>>(
        x, sums, cnt, W1p, b1, gamma, beta, prelu_a, W2p, b2, out);
}

// Round 3
// 392.859 us; speedup vs baseline: 1.7488x; 1.1810x over previous
//
#include <hip/hip_runtime.h>

#define NNODES 100000
#define NEDGES 600000
#define HDIM   128
#define H2     256
#define NB_SCAN 391   // ceil(NNODES/256)

typedef __attribute__((ext_vector_type(8))) short short8;
typedef __attribute__((ext_vector_type(4))) float f32x4;

static __device__ __forceinline__ ushort f32_to_bf16(float f) {
    union { float f; uint u; } c; c.f = f;
    uint u = c.u;
    return (ushort)((u + 0x7fffu + ((u >> 16) & 1u)) >> 16);
}

// ---------------------------------------------------------------------------
// CSR build: histogram -> 3-stage exclusive scan -> bucket fill
// ---------------------------------------------------------------------------
__global__ __launch_bounds__(256) void deg_count(
    const int* __restrict__ col, int* __restrict__ deg)
{
    int e = blockIdx.x * 256 + threadIdx.x;
    if (e < NEDGES) atomicAdd(&deg[col[e]], 1);
}

__global__ __launch_bounds__(256) void scan1(
    const int* __restrict__ deg, int* __restrict__ excl, int* __restrict__ bsum)
{
    __shared__ int s[256];
    int tid = threadIdx.x;
    int i = blockIdx.x * 256 + tid;
    int v = (i < NNODES) ? deg[i] : 0;
    s[tid] = v;
    __syncthreads();
    for (int off = 1; off < 256; off <<= 1) {
        int tv = (tid >= off) ? s[tid - off] : 0;
        __syncthreads();
        s[tid] += tv;
        __syncthreads();
    }
    if (i < NNODES) excl[i] = s[tid] - v;
    if (tid == 255) bsum[blockIdx.x] = s[255];
}

__global__ __launch_bounds__(512) void scan2(int* __restrict__ bsum)
{
    __shared__ int s[512];
    int t = threadIdx.x;
    int v = (t < NB_SCAN) ? bsum[t] : 0;
    s[t] = v;
    __syncthreads();
    for (int off = 1; off < 512; off <<= 1) {
        int u = (t >= off) ? s[t - off] : 0;
        __syncthreads();
        s[t] += u;
        __syncthreads();
    }
    if (t < NB_SCAN) bsum[t] = s[t] - v;   // exclusive block offsets
}

__global__ __launch_bounds__(256) void scan3(
    const int* __restrict__ excl, const int* __restrict__ bsum,
    int* __restrict__ off, int* __restrict__ cursor)
{
    int i = blockIdx.x * 256 + threadIdx.x;
    if (i < NNODES) {
        int o = excl[i] + bsum[blockIdx.x];
        off[i] = o;
        cursor[i] = o;
    }
}

__global__ __launch_bounds__(256) void fill_eid(
    const int* __restrict__ col, int* __restrict__ cursor, int* __restrict__ eid)
{
    int e = blockIdx.x * 256 + threadIdx.x;
    if (e < NEDGES) {
        int p = atomicAdd(&cursor[col[e]], 1);
        eid[p] = e;
    }
}

// ---------------------------------------------------------------------------
// Pack W [K][ncols] f32 row-major -> bf16 MFMA B-frag order.
// ---------------------------------------------------------------------------
__global__ __launch_bounds__(256) void pack_w(
    const float* __restrict__ W, ushort* __restrict__ Wp, int ncols, int total)
{
    int id = blockIdx.x * 256 + threadIdx.x;
    if (id >= total) return;
    int l  = id & 63;
    int ks = (id >> 6) & 7;
    int nt = id >> 9;
    int colc = nt * 16 + (l & 15);
    int kb   = ks * 32 + (l >> 4) * 8;
    short8 v;
#pragma unroll
    for (int j = 0; j < 8; ++j)
        v[j] = (short)f32_to_bf16(W[(size_t)(kb + j) * ncols + colc]);
    *(short8*)&Wp[(size_t)id * 8] = v;
}

// ---------------------------------------------------------------------------
// Fused: CSR gather-mean -> [x|agg] bf16 LDS tile -> GEMM1 -> LN -> PReLU
//        -> GEMM2 -> out.  64 rows/block, 256 threads (4 waves).
// ---------------------------------------------------------------------------
__global__ __launch_bounds__(256) void fused_mfma(
    const float*  __restrict__ x,
    const float*  __restrict__ edge_attr,
    const int*    __restrict__ off,
    const int*    __restrict__ deg,
    const int*    __restrict__ eid,
    const ushort* __restrict__ W1p,
    const float*  __restrict__ b1,
    const float*  __restrict__ gamma,
    const float*  __restrict__ beta,
    const float*  __restrict__ prelu_a,
    const ushort* __restrict__ W2p,
    const float*  __restrict__ b2,
    float*        __restrict__ out)
{
    __shared__ ushort hbuf[64 * 256];   // 32 KB bf16 tile (h_in, then h_mid)
    __shared__ float red_s[4][64];
    __shared__ float red_q[4][64];
    __shared__ float mu_l[64];
    __shared__ float rs_l[64];

    const int t = threadIdx.x;
    const int w = t >> 6;
    const int l = t & 63;
    const int lrow = l & 15;
    const int lk   = l >> 4;
    const int row0 = blockIdx.x * 64;

    // ---- Phase 1: gather-mean + x -> swizzled bf16 tile ------------------
    {
        const int grp = t >> 5;        // 8 groups of 32 lanes
        const int gl  = t & 31;
        const int c4  = gl * 4;        // 4 channels per lane
        for (int rr = 0; rr < 8; ++rr) {
            int lr = rr * 8 + grp;
            int row = row0 + lr;
            float4 xv = {0.f, 0.f, 0.f, 0.f};
            float4 av = {0.f, 0.f, 0.f, 0.f};
            if (row < NNODES) {
                xv = *(const float4*)&x[(size_t)row * HDIM + c4];
                int o  = off[row];
                int dg = deg[row];
                int pend = o + dg;
                int p = o;
                for (; p + 2 <= pend; p += 2) {      // 2-deep MLP
                    int e0 = eid[p], e1 = eid[p + 1];
                    float4 v0 = *(const float4*)&edge_attr[(size_t)e0 * HDIM + c4];
                    float4 v1 = *(const float4*)&edge_attr[(size_t)e1 * HDIM + c4];
                    av.x += v0.x + v1.x; av.y += v0.y + v1.y;
                    av.z += v0.z + v1.z; av.w += v0.w + v1.w;
                }
                if (p < pend) {
                    int e0 = eid[p];
                    float4 v0 = *(const float4*)&edge_attr[(size_t)e0 * HDIM + c4];
                    av.x += v0.x; av.y += v0.y; av.z += v0.z; av.w += v0.w;
                }
                float inv = 1.0f / fmaxf((float)dg, 1.0f);
                av.x *= inv; av.y *= inv; av.z *= inv; av.w *= inv;
            }
            uint xr = (uint)lr;
            uint idxX = ((xr << 8) + (uint)c4)         ^ ((xr & 7u) << 3);
            uint idxA = ((xr << 8) + (uint)(128 + c4)) ^ ((xr & 7u) << 3);
            ushort4 hx, ha;
            hx.x = f32_to_bf16(xv.x); hx.y = f32_to_bf16(xv.y);
            hx.z = f32_to_bf16(xv.z); hx.w = f32_to_bf16(xv.w);
            ha.x = f32_to_bf16(av.x); ha.y = f32_to_bf16(av.y);
            ha.z = f32_to_bf16(av.z); ha.w = f32_to_bf16(av.w);
            *(ushort4*)&hbuf[idxX] = hx;
            *(ushort4*)&hbuf[idxA] = ha;
        }
    }
    __syncthreads();

    // ---- Phase 2: GEMM1 — wave w owns cols [w*64, w*64+64) ---------------
    f32x4 acc[4][4];
#pragma unroll
    for (int i = 0; i < 4; ++i)
#pragma unroll
        for (int j = 0; j < 4; ++j) acc[i][j] = (f32x4)(0.0f);

#pragma unroll
    for (int ks = 0; ks < 8; ++ks) {
        short8 a[4];
#pragma unroll
        for (int rt = 0; rt < 4; ++rt) {
            uint row = (uint)(rt * 16 + lrow);
            uint idx = ((row << 8) + (uint)(ks * 32 + lk * 8)) ^ ((row & 7u) << 3);
            a[rt] = *(const short8*)&hbuf[idx];
        }
#pragma unroll
        for (int ct = 0; ct < 4; ++ct) {
            short8 b = *(const short8*)&W1p[(size_t)(((w * 4 + ct) * 8 + ks) * 64 + l) * 8];
#pragma unroll
            for (int rt = 0; rt < 4; ++rt)
                acc[rt][ct] = __builtin_amdgcn_mfma_f32_16x16x32_bf16(
                    a[rt], b, acc[rt][ct], 0, 0, 0);
        }
    }

    // ---- Phase 3: +bias, LN stats ----------------------------------------
    float b1c[4], g1c[4], be1c[4];
#pragma unroll
    for (int ct = 0; ct < 4; ++ct) {
        int colc = w * 64 + ct * 16 + lrow;
        b1c[ct] = b1[colc]; g1c[ct] = gamma[colc]; be1c[ct] = beta[colc];
    }
#pragma unroll
    for (int rt = 0; rt < 4; ++rt)
#pragma unroll
        for (int ct = 0; ct < 4; ++ct)
#pragma unroll
            for (int r = 0; r < 4; ++r) acc[rt][ct][r] += b1c[ct];

#pragma unroll
    for (int rt = 0; rt < 4; ++rt) {
        float s[4], qq[4];
#pragma unroll
        for (int r = 0; r < 4; ++r) {
            float v0 = acc[rt][0][r], v1 = acc[rt][1][r];
            float v2 = acc[rt][2][r], v3 = acc[rt][3][r];
            s[r]  = v0 + v1 + v2 + v3;
            qq[r] = v0*v0 + v1*v1 + v2*v2 + v3*v3;
        }
#pragma unroll
        for (int off2 = 1; off2 < 16; off2 <<= 1) {
#pragma unroll
            for (int r = 0; r < 4; ++r) {
                s[r]  += __shfl_xor(s[r],  off2, 64);
                qq[r] += __shfl_xor(qq[r], off2, 64);
            }
        }
        if (lrow == 0) {
#pragma unroll
            for (int r = 0; r < 4; ++r) {
                int row = rt * 16 + lk * 4 + r;
                red_s[w][row] = s[r];
                red_q[w][row] = qq[r];
            }
        }
    }
    __syncthreads();
    if (t < 64) {
        float s  = red_s[0][t] + red_s[1][t] + red_s[2][t] + red_s[3][t];
        float qq = red_q[0][t] + red_q[1][t] + red_q[2][t] + red_q[3][t];
        float mu  = s * (1.0f / H2);
        float var = qq * (1.0f / H2) - mu * mu;
        mu_l[t] = mu;
        rs_l[t] = rsqrtf(var + 1e-5f);
    }
    const float ap = prelu_a[0];
    __syncthreads();

    // ---- Phase 3b: normalize + PReLU -> h_mid bf16 (same LDS) ------------
#pragma unroll
    for (int rt = 0; rt < 4; ++rt) {
#pragma unroll
        for (int r = 0; r < 4; ++r) {
            uint row = (uint)(rt * 16 + lk * 4 + r);
            float mu = mu_l[row], rs = rs_l[row];
#pragma unroll
            for (int ct = 0; ct < 4; ++ct) {
                uint colc = (uint)(w * 64 + ct * 16 + lrow);
                float v = (acc[rt][ct][r] - mu) * rs * g1c[ct] + be1c[ct];
                v = v >= 0.0f ? v : ap * v;
                uint idx = ((row << 8) + colc) ^ ((row & 7u) << 3);
                hbuf[idx] = f32_to_bf16(v);
            }
        }
    }
    __syncthreads();

    // ---- Phase 4: GEMM2 — wave w owns cols [w*32, w*32+32) ---------------
    f32x4 acc2[4][2];
#pragma unroll
    for (int i = 0; i < 4; ++i)
#pragma unroll
        for (int j = 0; j < 2; ++j) acc2[i][j] = (f32x4)(0.0f);

#pragma unroll
    for (int ks = 0; ks < 8; ++ks) {
        short8 a[4];
#pragma unroll
        for (int rt = 0; rt < 4; ++rt) {
            uint row = (uint)(rt * 16 + lrow);
            uint idx = ((row << 8) + (uint)(ks * 32 + lk * 8)) ^ ((row & 7u) << 3);
            a[rt] = *(const short8*)&hbuf[idx];
        }
#pragma unroll
        for (int ct = 0; ct < 2; ++ct) {
            short8 b = *(const short8*)&W2p[(size_t)(((w * 2 + ct) * 8 + ks) * 64 + l) * 8];
#pragma unroll
            for (int rt = 0; rt < 4; ++rt)
                acc2[rt][ct] = __builtin_amdgcn_mfma_f32_16x16x32_bf16(
                    a[rt], b, acc2[rt][ct], 0, 0, 0);
        }
    }

    float b2c[2];
#pragma unroll
    for (int ct = 0; ct < 2; ++ct) b2c[ct] = b2[w * 32 + ct * 16 + lrow];

#pragma unroll
    for (int rt = 0; rt < 4; ++rt)
#pragma unroll
        for (int ct = 0; ct < 2; ++ct)
#pragma unroll
            for (int r = 0; r < 4; ++r) {
                int row = row0 + rt * 16 + lk * 4 + r;
                if (row < NNODES)
                    out[(size_t)row * HDIM + w * 32 + ct * 16 + lrow] =
                        acc2[rt][ct][r] + b2c[ct];
            }
}

// ---------------------------------------------------------------------------
extern "C" void kernel_launch(void* const* d_in, const int* in_sizes, int n_in,
                              void* d_out, int out_size, void* d_ws, size_t ws_size,
                              hipStream_t stream)
{
    const float* x         = (const float*)d_in[0];
    const int*   ei        = (const int*)  d_in[1];
    const float* edge_attr = (const float*)d_in[2];
    const float* W1        = (const float*)d_in[3];
    const float* b1        = (const float*)d_in[4];
    const float* gamma     = (const float*)d_in[5];
    const float* beta      = (const float*)d_in[6];
    const float* prelu_a   = (const float*)d_in[7];
    const float* W2        = (const float*)d_in[8];
    const float* b2        = (const float*)d_in[9];
    float*       out       = (float*)d_out;

    int* deg    = (int*)d_ws;            // [NNODES]
    int* excl   = deg + NNODES;          // [NNODES]
    int* bsum   = excl + NNODES;         // [512]
    int* off    = bsum + 512;            // [NNODES]
    int* cursor = off + NNODES;          // [NNODES]
    int* eid    = cursor + NNODES;       // [NEDGES]
    ushort* W1p = (ushort*)(eid + NEDGES);      // 16*8*64*8 elems (128 KB)
    ushort* W2p = W1p + 16 * 8 * 64 * 8;        //  8*8*64*8 elems (64 KB)

    const int* colp = ei + NEDGES;       // edge_index[1]

    hipMemsetAsync(deg, 0, NNODES * sizeof(int), stream);

    deg_count<<<(NEDGES + 255) / 256, 256, 0, stream>>>(colp, deg);
    scan1<<<NB_SCAN, 256, 0, stream>>>(deg, excl, bsum);
    scan2<<<1, 512, 0, stream>>>(bsum);
    scan3<<<NB_SCAN, 256, 0, stream>>>(excl, bsum, off, cursor);
    fill_eid<<<(NEDGES + 255) / 256, 256, 0, stream>>>(colp, cursor, eid);

    pack_w<<<32, 256, 0, stream>>>(W1, W1p, H2,   16 * 8 * 64);
    pack_w<<<16, 256, 0, stream>>>(W2, W2p, HDIM,  8 * 8 * 64);

    fused_mfma<<<(NNODES + 63) / 64, 256, 0, stream>>>(
        x, edge_attr, off, deg, eid,
        W1p, b1, gamma, beta, prelu_a, W2p, b2, out);
}

// Round 4
// 308.609 us; speedup vs baseline: 2.2262x; 1.2730x over previous
//
#include <hip/hip_runtime.h>

#define NNODES 100000
#define NEDGES 600000
#define HDIM   128
#define H2     256
#define NB_SCAN 391   // ceil(NNODES/256)

typedef __attribute__((ext_vector_type(8))) short short8;
typedef __attribute__((ext_vector_type(4))) float f32x4;

static __device__ __forceinline__ ushort f32_to_bf16(float f) {
    union { float f; uint u; } c; c.f = f;
    uint u = c.u;
    return (ushort)((u + 0x7fffu + ((u >> 16) & 1u)) >> 16);
}

// ---------------------------------------------------------------------------
// CSR build: histogram -> 3-stage exclusive scan -> bucket fill
// ---------------------------------------------------------------------------
__global__ __launch_bounds__(256) void deg_count(
    const int* __restrict__ col, int* __restrict__ deg)
{
    int e = blockIdx.x * 256 + threadIdx.x;
    if (e < NEDGES) atomicAdd(&deg[col[e]], 1);
}

__global__ __launch_bounds__(256) void scan1(
    const int* __restrict__ deg, int* __restrict__ excl, int* __restrict__ bsum)
{
    __shared__ int s[256];
    int tid = threadIdx.x;
    int i = blockIdx.x * 256 + tid;
    int v = (i < NNODES) ? deg[i] : 0;
    s[tid] = v;
    __syncthreads();
    for (int off = 1; off < 256; off <<= 1) {
        int tv = (tid >= off) ? s[tid - off] : 0;
        __syncthreads();
        s[tid] += tv;
        __syncthreads();
    }
    if (i < NNODES) excl[i] = s[tid] - v;
    if (tid == 255) bsum[blockIdx.x] = s[255];
}

__global__ __launch_bounds__(512) void scan2(int* __restrict__ bsum)
{
    __shared__ int s[512];
    int t = threadIdx.x;
    int v = (t < NB_SCAN) ? bsum[t] : 0;
    s[t] = v;
    __syncthreads();
    for (int off = 1; off < 512; off <<= 1) {
        int u = (t >= off) ? s[t - off] : 0;
        __syncthreads();
        s[t] += u;
        __syncthreads();
    }
    if (t < NB_SCAN) bsum[t] = s[t] - v;   // exclusive block offsets
}

__global__ __launch_bounds__(256) void scan3(
    const int* __restrict__ excl, const int* __restrict__ bsum,
    int* __restrict__ off, int* __restrict__ cursor)
{
    int i = blockIdx.x * 256 + threadIdx.x;
    if (i < NNODES) {
        int o = excl[i] + bsum[blockIdx.x];
        off[i] = o;
        cursor[i] = o;
    }
}

__global__ __launch_bounds__(256) void fill_eid(
    const int* __restrict__ col, int* __restrict__ cursor, int* __restrict__ eid)
{
    int e = blockIdx.x * 256 + threadIdx.x;
    if (e < NEDGES) {
        int p = atomicAdd(&cursor[col[e]], 1);
        eid[p] = e;
    }
}

// ---------------------------------------------------------------------------
// Gather-mean, high-TLP: one 32-lane group per node, batch-4 edge loads.
// agg[node][c] = mean of edge_attr over CSR segment, bf16 output.
// ---------------------------------------------------------------------------
__global__ __launch_bounds__(256) void gather_mean(
    const float* __restrict__ edge_attr,
    const int*   __restrict__ off,
    const int*   __restrict__ deg,
    const int*   __restrict__ eid,
    ushort*      __restrict__ agg)
{
    int gid = blockIdx.x * 256 + threadIdx.x;
    int node = gid >> 5;
    if (node >= NNODES) return;
    int gl = gid & 31;
    int c4 = gl * 4;

    int o  = off[node];
    int dg = deg[node];
    float4 av = {0.f, 0.f, 0.f, 0.f};

    int p = 0;
    for (; p + 4 <= dg; p += 4) {
        int e0 = eid[o + p + 0], e1 = eid[o + p + 1];
        int e2 = eid[o + p + 2], e3 = eid[o + p + 3];
        float4 v0 = *(const float4*)&edge_attr[(size_t)e0 * HDIM + c4];
        float4 v1 = *(const float4*)&edge_attr[(size_t)e1 * HDIM + c4];
        float4 v2 = *(const float4*)&edge_attr[(size_t)e2 * HDIM + c4];
        float4 v3 = *(const float4*)&edge_attr[(size_t)e3 * HDIM + c4];
        av.x += (v0.x + v1.x) + (v2.x + v3.x);
        av.y += (v0.y + v1.y) + (v2.y + v3.y);
        av.z += (v0.z + v1.z) + (v2.z + v3.z);
        av.w += (v0.w + v1.w) + (v2.w + v3.w);
    }
    for (; p < dg; ++p) {
        int e0 = eid[o + p];
        float4 v0 = *(const float4*)&edge_attr[(size_t)e0 * HDIM + c4];
        av.x += v0.x; av.y += v0.y; av.z += v0.z; av.w += v0.w;
    }
    float inv = 1.0f / fmaxf((float)dg, 1.0f);
    ushort4 hv;
    hv.x = f32_to_bf16(av.x * inv); hv.y = f32_to_bf16(av.y * inv);
    hv.z = f32_to_bf16(av.z * inv); hv.w = f32_to_bf16(av.w * inv);
    *(ushort4*)&agg[(size_t)node * HDIM + c4] = hv;
}

// ---------------------------------------------------------------------------
// Pack W [K][ncols] f32 row-major -> bf16 MFMA B-frag order.
// ---------------------------------------------------------------------------
__global__ __launch_bounds__(256) void pack_w(
    const float* __restrict__ W, ushort* __restrict__ Wp, int ncols, int total)
{
    int id = blockIdx.x * 256 + threadIdx.x;
    if (id >= total) return;
    int l  = id & 63;
    int ks = (id >> 6) & 7;
    int nt = id >> 9;
    int colc = nt * 16 + (l & 15);
    int kb   = ks * 32 + (l >> 4) * 8;
    short8 v;
#pragma unroll
    for (int j = 0; j < 8; ++j)
        v[j] = (short)f32_to_bf16(W[(size_t)(kb + j) * ncols + colc]);
    *(short8*)&Wp[(size_t)id * 8] = v;
}

// ---------------------------------------------------------------------------
// Fused: [x|agg] bf16 LDS tile (linear reads) -> GEMM1 -> LN -> PReLU
//        -> GEMM2 -> out.  64 rows/block, 256 threads (4 waves).
// ---------------------------------------------------------------------------
__global__ __launch_bounds__(256) void fused_mfma(
    const float*  __restrict__ x,
    const ushort* __restrict__ agg,
    const ushort* __restrict__ W1p,
    const float*  __restrict__ b1,
    const float*  __restrict__ gamma,
    const float*  __restrict__ beta,
    const float*  __restrict__ prelu_a,
    const ushort* __restrict__ W2p,
    const float*  __restrict__ b2,
    float*        __restrict__ out)
{
    __shared__ ushort hbuf[64 * 256];   // 32 KB bf16 tile (h_in, then h_mid)
    __shared__ float red_s[4][64];
    __shared__ float red_q[4][64];
    __shared__ float mu_l[64];
    __shared__ float rs_l[64];

    const int t = threadIdx.x;
    const int w = t >> 6;
    const int l = t & 63;
    const int lrow = l & 15;
    const int lk   = l >> 4;
    const int row0 = blockIdx.x * 64;

    // ---- Phase 1: stream x (f32) + agg (bf16) -> swizzled bf16 tile ------
    {
        const int sub = t >> 6;    // 0..3: row offset within group of 4
        const int q   = t & 63;    // 64 lanes per row
        for (int it = 0; it < 16; ++it) {
            int lr = it * 4 + sub;
            int row = row0 + lr; if (row >= NNODES) row = NNODES - 1;
            ushort4 hv;
            uint cbase;
            if (q < 32) {
                float4 v = *(const float4*)&x[(size_t)row * HDIM + q * 4];
                hv.x = f32_to_bf16(v.x); hv.y = f32_to_bf16(v.y);
                hv.z = f32_to_bf16(v.z); hv.w = f32_to_bf16(v.w);
                cbase = (uint)(q * 4);
            } else {
                hv = *(const ushort4*)&agg[(size_t)row * HDIM + (q - 32) * 4];
                cbase = (uint)(128 + (q - 32) * 4);
            }
            uint idx = (((uint)lr << 8) + cbase) ^ (((uint)lr & 7u) << 3);
            *(ushort4*)&hbuf[idx] = hv;
        }
    }
    __syncthreads();

    // ---- Phase 2: GEMM1 — wave w owns cols [w*64, w*64+64) ---------------
    f32x4 acc[4][4];
#pragma unroll
    for (int i = 0; i < 4; ++i)
#pragma unroll
        for (int j = 0; j < 4; ++j) acc[i][j] = (f32x4)(0.0f);

#pragma unroll
    for (int ks = 0; ks < 8; ++ks) {
        short8 a[4];
#pragma unroll
        for (int rt = 0; rt < 4; ++rt) {
            uint row = (uint)(rt * 16 + lrow);
            uint idx = ((row << 8) + (uint)(ks * 32 + lk * 8)) ^ ((row & 7u) << 3);
            a[rt] = *(const short8*)&hbuf[idx];
        }
#pragma unroll
        for (int ct = 0; ct < 4; ++ct) {
            short8 b = *(const short8*)&W1p[(size_t)(((w * 4 + ct) * 8 + ks) * 64 + l) * 8];
#pragma unroll
            for (int rt = 0; rt < 4; ++rt)
                acc[rt][ct] = __builtin_amdgcn_mfma_f32_16x16x32_bf16(
                    a[rt], b, acc[rt][ct], 0, 0, 0);
        }
    }

    // ---- Phase 3: +bias, LN stats ----------------------------------------
    float b1c[4], g1c[4], be1c[4];
#pragma unroll
    for (int ct = 0; ct < 4; ++ct) {
        int colc = w * 64 + ct * 16 + lrow;
        b1c[ct] = b1[colc]; g1c[ct] = gamma[colc]; be1c[ct] = beta[colc];
    }
#pragma unroll
    for (int rt = 0; rt < 4; ++rt)
#pragma unroll
        for (int ct = 0; ct < 4; ++ct)
#pragma unroll
            for (int r = 0; r < 4; ++r) acc[rt][ct][r] += b1c[ct];

#pragma unroll
    for (int rt = 0; rt < 4; ++rt) {
        float s[4], qq[4];
#pragma unroll
        for (int r = 0; r < 4; ++r) {
            float v0 = acc[rt][0][r], v1 = acc[rt][1][r];
            float v2 = acc[rt][2][r], v3 = acc[rt][3][r];
            s[r]  = v0 + v1 + v2 + v3;
            qq[r] = v0*v0 + v1*v1 + v2*v2 + v3*v3;
        }
#pragma unroll
        for (int off2 = 1; off2 < 16; off2 <<= 1) {
#pragma unroll
            for (int r = 0; r < 4; ++r) {
                s[r]  += __shfl_xor(s[r],  off2, 64);
                qq[r] += __shfl_xor(qq[r], off2, 64);
            }
        }
        if (lrow == 0) {
#pragma unroll
            for (int r = 0; r < 4; ++r) {
                int row = rt * 16 + lk * 4 + r;
                red_s[w][row] = s[r];
                red_q[w][row] = qq[r];
            }
        }
    }
    __syncthreads();
    if (t < 64) {
        float s  = red_s[0][t] + red_s[1][t] + red_s[2][t] + red_s[3][t];
        float qq = red_q[0][t] + red_q[1][t] + red_q[2][t] + red_q[3][t];
        float mu  = s * (1.0f / H2);
        float var = qq * (1.0f / H2) - mu * mu;
        mu_l[t] = mu;
        rs_l[t] = rsqrtf(var + 1e-5f);
    }
    const float ap = prelu_a[0];
    __syncthreads();

    // ---- Phase 3b: normalize + PReLU -> h_mid bf16 (same LDS) ------------
#pragma unroll
    for (int rt = 0; rt < 4; ++rt) {
#pragma unroll
        for (int r = 0; r < 4; ++r) {
            uint row = (uint)(rt * 16 + lk * 4 + r);
            float mu = mu_l[row], rs = rs_l[row];
#pragma unroll
            for (int ct = 0; ct < 4; ++ct) {
                uint colc = (uint)(w * 64 + ct * 16 + lrow);
                float v = (acc[rt][ct][r] - mu) * rs * g1c[ct] + be1c[ct];
                v = v >= 0.0f ? v : ap * v;
                uint idx = ((row << 8) + colc) ^ ((row & 7u) << 3);
                hbuf[idx] = f32_to_bf16(v);
            }
        }
    }
    __syncthreads();

    // ---- Phase 4: GEMM2 — wave w owns cols [w*32, w*32+32) ---------------
    f32x4 acc2[4][2];
#pragma unroll
    for (int i = 0; i < 4; ++i)
#pragma unroll
        for (int j = 0; j < 2; ++j) acc2[i][j] = (f32x4)(0.0f);

#pragma unroll
    for (int ks = 0; ks < 8; ++ks) {
        short8 a[4];
#pragma unroll
        for (int rt = 0; rt < 4; ++rt) {
            uint row = (uint)(rt * 16 + lrow);
            uint idx = ((row << 8) + (uint)(ks * 32 + lk * 8)) ^ ((row & 7u) << 3);
            a[rt] = *(const short8*)&hbuf[idx];
        }
#pragma unroll
        for (int ct = 0; ct < 2; ++ct) {
            short8 b = *(const short8*)&W2p[(size_t)(((w * 2 + ct) * 8 + ks) * 64 + l) * 8];
#pragma unroll
            for (int rt = 0; rt < 4; ++rt)
                acc2[rt][ct] = __builtin_amdgcn_mfma_f32_16x16x32_bf16(
                    a[rt], b, acc2[rt][ct], 0, 0, 0);
        }
    }

    float b2c[2];
#pragma unroll
    for (int ct = 0; ct < 2; ++ct) b2c[ct] = b2[w * 32 + ct * 16 + lrow];

#pragma unroll
    for (int rt = 0; rt < 4; ++rt)
#pragma unroll
        for (int ct = 0; ct < 2; ++ct)
#pragma unroll
            for (int r = 0; r < 4; ++r) {
                int row = row0 + rt * 16 + lk * 4 + r;
                if (row < NNODES)
                    out[(size_t)row * HDIM + w * 32 + ct * 16 + lrow] =
                        acc2[rt][ct][r] + b2c[ct];
            }
}

// ---------------------------------------------------------------------------
extern "C" void kernel_launch(void* const* d_in, const int* in_sizes, int n_in,
                              void* d_out, int out_size, void* d_ws, size_t ws_size,
                              hipStream_t stream)
{
    const float* x         = (const float*)d_in[0];
    const int*   ei        = (const int*)  d_in[1];
    const float* edge_attr = (const float*)d_in[2];
    const float* W1        = (const float*)d_in[3];
    const float* b1        = (const float*)d_in[4];
    const float* gamma     = (const float*)d_in[5];
    const float* beta      = (const float*)d_in[6];
    const float* prelu_a   = (const float*)d_in[7];
    const float* W2        = (const float*)d_in[8];
    const float* b2        = (const float*)d_in[9];
    float*       out       = (float*)d_out;

    int* deg    = (int*)d_ws;            // [NNODES]
    int* excl   = deg + NNODES;          // [NNODES]
    int* bsum   = excl + NNODES;         // [512]
    int* off    = bsum + 512;            // [NNODES]
    int* cursor = off + NNODES;          // [NNODES]
    int* eid    = cursor + NNODES;       // [NEDGES]
    ushort* W1p = (ushort*)(eid + NEDGES);      // 16*8*64*8 elems (128 KB)
    ushort* W2p = W1p + 16 * 8 * 64 * 8;        //  8*8*64*8 elems (64 KB)
    ushort* agg = W2p + 8 * 8 * 64 * 8;         // [NNODES*HDIM] bf16 (25.6 MB)

    const int* colp = ei + NEDGES;       // edge_index[1]

    hipMemsetAsync(deg, 0, NNODES * sizeof(int), stream);

    deg_count<<<(NEDGES + 255) / 256, 256, 0, stream>>>(colp, deg);
    scan1<<<NB_SCAN, 256, 0, stream>>>(deg, excl, bsum);
    scan2<<<1, 512, 0, stream>>>(bsum);
    scan3<<<NB_SCAN, 256, 0, stream>>>(excl, bsum, off, cursor);
    fill_eid<<<(NEDGES + 255) / 256, 256, 0, stream>>>(colp, cursor, eid);

    gather_mean<<<(NNODES * 32 + 255) / 256, 256, 0, stream>>>(
        edge_attr, off, deg, eid, agg);

    pack_w<<<32, 256, 0, stream>>>(W1, W1p, H2,   16 * 8 * 64);
    pack_w<<<16, 256, 0, stream>>>(W2, W2p, HDIM,  8 * 8 * 64);

    fused_mfma<<<(NNODES + 63) / 64, 256, 0, stream>>>(
        x, agg, W1p, b1, gamma, beta, prelu_a, W2p, b2, out);
}

// Round 6
// 280.506 us; speedup vs baseline: 2.4492x; 1.1002x over previous
//
#include <hip/hip_runtime.h>

#define NNODES 100000
#define NEDGES 600000
#define HDIM   128
#define H2     256
#define NB_SCAN 391   // ceil(NNODES/256)

typedef __attribute__((ext_vector_type(8))) short short8;
typedef __attribute__((ext_vector_type(4))) float f32x4;
typedef __attribute__((ext_vector_type(2))) float f32x2;

static __device__ __forceinline__ ushort f32_to_bf16(float f) {
    union { float f; uint u; } c; c.f = f;
    uint u = c.u;
    return (ushort)((u + 0x7fffu + ((u >> 16) & 1u)) >> 16);
}

// ---------------------------------------------------------------------------
// Zero the degree array (replaces hipMemsetAsync / rocclr fill in the graph).
// ---------------------------------------------------------------------------
__global__ __launch_bounds__(256) void zero_deg(int* __restrict__ deg)
{
    int i = blockIdx.x * 256 + threadIdx.x;
    if (i < NNODES) deg[i] = 0;
}

// ---------------------------------------------------------------------------
// CSR build: histogram -> 3-stage exclusive scan -> bucket fill
// ---------------------------------------------------------------------------
__global__ __launch_bounds__(256) void deg_count(
    const int* __restrict__ col, int* __restrict__ deg)
{
    int e = blockIdx.x * 256 + threadIdx.x;
    if (e < NEDGES) atomicAdd(&deg[col[e]], 1);
}

__global__ __launch_bounds__(256) void scan1(
    const int* __restrict__ deg, int* __restrict__ excl, int* __restrict__ bsum)
{
    __shared__ int s[256];
    int tid = threadIdx.x;
    int i = blockIdx.x * 256 + tid;
    int v = (i < NNODES) ? deg[i] : 0;
    s[tid] = v;
    __syncthreads();
    for (int off = 1; off < 256; off <<= 1) {
        int tv = (tid >= off) ? s[tid - off] : 0;
        __syncthreads();
        s[tid] += tv;
        __syncthreads();
    }
    if (i < NNODES) excl[i] = s[tid] - v;
    if (tid == 255) bsum[blockIdx.x] = s[255];
}

__global__ __launch_bounds__(512) void scan2(int* __restrict__ bsum)
{
    __shared__ int s[512];
    int t = threadIdx.x;
    int v = (t < NB_SCAN) ? bsum[t] : 0;
    s[t] = v;
    __syncthreads();
    for (int off = 1; off < 512; off <<= 1) {
        int u = (t >= off) ? s[t - off] : 0;
        __syncthreads();
        s[t] += u;
        __syncthreads();
    }
    if (t < NB_SCAN) bsum[t] = s[t] - v;   // exclusive block offsets
}

__global__ __launch_bounds__(256) void scan3(
    const int* __restrict__ excl, const int* __restrict__ bsum,
    int* __restrict__ off, int* __restrict__ cursor)
{
    int i = blockIdx.x * 256 + threadIdx.x;
    if (i < NNODES) {
        int o = excl[i] + bsum[blockIdx.x];
        off[i] = o;
        cursor[i] = o;
    }
}

__global__ __launch_bounds__(256) void fill_eid(
    const int* __restrict__ col, int* __restrict__ cursor, int* __restrict__ eid)
{
    int e = blockIdx.x * 256 + threadIdx.x;
    if (e < NEDGES) {
        int p = atomicAdd(&cursor[col[e]], 1);
        eid[p] = e;
    }
}

// ---------------------------------------------------------------------------
// Gather-mean: ONE 64-lane WAVE per node. CSR metadata scalar via
// readfirstlane (wave-uniform branches, no divergence). Each lane owns 2
// channels (f32x2, 8 B) -> one 512 B transaction per edge row. Batch-4
// independent loads in flight; nontemporal reads keep the 307 MB edge
// stream from thrashing L2.
// ---------------------------------------------------------------------------
__global__ __launch_bounds__(256) void gather_mean(
    const float* __restrict__ edge_attr,
    const int*   __restrict__ off,
    const int*   __restrict__ deg,
    const int*   __restrict__ eid,
    ushort*      __restrict__ agg)
{
    int wid = (blockIdx.x * 256 + threadIdx.x) >> 6;   // wave id = node
    if (wid >= NNODES) return;
    const int l  = threadIdx.x & 63;
    const int c2 = l * 2;

    const int o  = __builtin_amdgcn_readfirstlane(off[wid]);
    const int dg = __builtin_amdgcn_readfirstlane(deg[wid]);

    f32x2 av = {0.f, 0.f};
    int p = 0;
    for (; p + 4 <= dg; p += 4) {
        int e0 = __builtin_amdgcn_readfirstlane(eid[o + p + 0]);
        int e1 = __builtin_amdgcn_readfirstlane(eid[o + p + 1]);
        int e2 = __builtin_amdgcn_readfirstlane(eid[o + p + 2]);
        int e3 = __builtin_amdgcn_readfirstlane(eid[o + p + 3]);
        f32x2 v0 = __builtin_nontemporal_load(
            (const f32x2*)&edge_attr[(size_t)e0 * HDIM + c2]);
        f32x2 v1 = __builtin_nontemporal_load(
            (const f32x2*)&edge_attr[(size_t)e1 * HDIM + c2]);
        f32x2 v2 = __builtin_nontemporal_load(
            (const f32x2*)&edge_attr[(size_t)e2 * HDIM + c2]);
        f32x2 v3 = __builtin_nontemporal_load(
            (const f32x2*)&edge_attr[(size_t)e3 * HDIM + c2]);
        av += (v0 + v1) + (v2 + v3);
    }
    for (; p < dg; ++p) {
        int e0 = __builtin_amdgcn_readfirstlane(eid[o + p]);
        f32x2 v0 = __builtin_nontemporal_load(
            (const f32x2*)&edge_attr[(size_t)e0 * HDIM + c2]);
        av += v0;
    }
    float inv = 1.0f / fmaxf((float)dg, 1.0f);
    ushort2 hv;
    hv.x = f32_to_bf16(av.x * inv);
    hv.y = f32_to_bf16(av.y * inv);
    *(ushort2*)&agg[(size_t)wid * HDIM + c2] = hv;
}

// ---------------------------------------------------------------------------
// Pack both weight matrices in ONE dispatch.
// Wp[((nt*8 + ks)*64 + lane)*8 + j] = bf16(W[ks*32 + (lane>>4)*8 + j][nt*16 + (lane&15)])
// ---------------------------------------------------------------------------
__device__ __forceinline__ void pack_one(
    const float* __restrict__ W, ushort* __restrict__ Wp, int ncols, int id)
{
    int l  = id & 63;
    int ks = (id >> 6) & 7;
    int nt = id >> 9;
    int colc = nt * 16 + (l & 15);
    int kb   = ks * 32 + (l >> 4) * 8;
    short8 v;
#pragma unroll
    for (int j = 0; j < 8; ++j)
        v[j] = (short)f32_to_bf16(W[(size_t)(kb + j) * ncols + colc]);
    *(short8*)&Wp[(size_t)id * 8] = v;
}

__global__ __launch_bounds__(256) void pack_both(
    const float* __restrict__ W1, const float* __restrict__ W2,
    ushort* __restrict__ W1p, ushort* __restrict__ W2p)
{
    int id = blockIdx.x * 256 + threadIdx.x;
    if (id < 16 * 8 * 64)            pack_one(W1, W1p, H2,   id);
    else if (id < 24 * 8 * 64)       pack_one(W2, W2p, HDIM, id - 16 * 8 * 64);
}

// ---------------------------------------------------------------------------
// Fused: [x|agg] bf16 LDS tile -> GEMM1 -> LN -> PReLU -> GEMM2 -> out.
// 64 rows/block, 256 threads (4 waves).
// ---------------------------------------------------------------------------
__global__ __launch_bounds__(256) void fused_mfma(
    const float*  __restrict__ x,
    const ushort* __restrict__ agg,
    const ushort* __restrict__ W1p,
    const float*  __restrict__ b1,
    const float*  __restrict__ gamma,
    const float*  __restrict__ beta,
    const float*  __restrict__ prelu_a,
    const ushort* __restrict__ W2p,
    const float*  __restrict__ b2,
    float*        __restrict__ out)
{
    __shared__ ushort hbuf[64 * 256];   // 32 KB bf16 tile (h_in, then h_mid)
    __shared__ float red_s[4][64];
    __shared__ float red_q[4][64];
    __shared__ float mu_l[64];
    __shared__ float rs_l[64];

    const int t = threadIdx.x;
    const int w = t >> 6;
    const int l = t & 63;
    const int lrow = l & 15;
    const int lk   = l >> 4;
    const int row0 = blockIdx.x * 64;

    // ---- Phase 1: stream x (f32) + agg (bf16) -> swizzled bf16 tile ------
    {
        const int sub = t >> 6;
        const int q   = t & 63;
        for (int it = 0; it < 16; ++it) {
            int lr = it * 4 + sub;
            int row = row0 + lr; if (row >= NNODES) row = NNODES - 1;
            ushort4 hv;
            uint cbase;
            if (q < 32) {
                float4 v = *(const float4*)&x[(size_t)row * HDIM + q * 4];
                hv.x = f32_to_bf16(v.x); hv.y = f32_to_bf16(v.y);
                hv.z = f32_to_bf16(v.z); hv.w = f32_to_bf16(v.w);
                cbase = (uint)(q * 4);
            } else {
                hv = *(const ushort4*)&agg[(size_t)row * HDIM + (q - 32) * 4];
                cbase = (uint)(128 + (q - 32) * 4);
            }
            uint idx = (((uint)lr << 8) + cbase) ^ (((uint)lr & 7u) << 3);
            *(ushort4*)&hbuf[idx] = hv;
        }
    }
    __syncthreads();

    // ---- Phase 2: GEMM1 — wave w owns cols [w*64, w*64+64) ---------------
    f32x4 acc[4][4];
#pragma unroll
    for (int i = 0; i < 4; ++i)
#pragma unroll
        for (int j = 0; j < 4; ++j) acc[i][j] = (f32x4)(0.0f);

#pragma unroll
    for (int ks = 0; ks < 8; ++ks) {
        short8 a[4];
#pragma unroll
        for (int rt = 0; rt < 4; ++rt) {
            uint row = (uint)(rt * 16 + lrow);
            uint idx = ((row << 8) + (uint)(ks * 32 + lk * 8)) ^ ((row & 7u) << 3);
            a[rt] = *(const short8*)&hbuf[idx];
        }
#pragma unroll
        for (int ct = 0; ct < 4; ++ct) {
            short8 b = *(const short8*)&W1p[(size_t)(((w * 4 + ct) * 8 + ks) * 64 + l) * 8];
#pragma unroll
            for (int rt = 0; rt < 4; ++rt)
                acc[rt][ct] = __builtin_amdgcn_mfma_f32_16x16x32_bf16(
                    a[rt], b, acc[rt][ct], 0, 0, 0);
        }
    }

    // ---- Phase 3: +bias, LN stats ----------------------------------------
    float b1c[4], g1c[4], be1c[4];
#pragma unroll
    for (int ct = 0; ct < 4; ++ct) {
        int colc = w * 64 + ct * 16 + lrow;
        b1c[ct] = b1[colc]; g1c[ct] = gamma[colc]; be1c[ct] = beta[colc];
    }
#pragma unroll
    for (int rt = 0; rt < 4; ++rt)
#pragma unroll
        for (int ct = 0; ct < 4; ++ct)
#pragma unroll
            for (int r = 0; r < 4; ++r) acc[rt][ct][r] += b1c[ct];

#pragma unroll
    for (int rt = 0; rt < 4; ++rt) {
        float s[4], qq[4];
#pragma unroll
        for (int r = 0; r < 4; ++r) {
            float v0 = acc[rt][0][r], v1 = acc[rt][1][r];
            float v2 = acc[rt][2][r], v3 = acc[rt][3][r];
            s[r]  = v0 + v1 + v2 + v3;
            qq[r] = v0*v0 + v1*v1 + v2*v2 + v3*v3;
        }
#pragma unroll
        for (int off2 = 1; off2 < 16; off2 <<= 1) {
#pragma unroll
            for (int r = 0; r < 4; ++r) {
                s[r]  += __shfl_xor(s[r],  off2, 64);
                qq[r] += __shfl_xor(qq[r], off2, 64);
            }
        }
        if (lrow == 0) {
#pragma unroll
            for (int r = 0; r < 4; ++r) {
                int row = rt * 16 + lk * 4 + r;
                red_s[w][row] = s[r];
                red_q[w][row] = qq[r];
            }
        }
    }
    __syncthreads();
    if (t < 64) {
        float s  = red_s[0][t] + red_s[1][t] + red_s[2][t] + red_s[3][t];
        float qq = red_q[0][t] + red_q[1][t] + red_q[2][t] + red_q[3][t];
        float mu  = s * (1.0f / H2);
        float var = qq * (1.0f / H2) - mu * mu;
        mu_l[t] = mu;
        rs_l[t] = rsqrtf(var + 1e-5f);
    }
    const float ap = prelu_a[0];
    __syncthreads();

    // ---- Phase 3b: normalize + PReLU -> h_mid bf16 (same LDS) ------------
#pragma unroll
    for (int rt = 0; rt < 4; ++rt) {
#pragma unroll
        for (int r = 0; r < 4; ++r) {
            uint row = (uint)(rt * 16 + lk * 4 + r);
            float mu = mu_l[row], rs = rs_l[row];
#pragma unroll
            for (int ct = 0; ct < 4; ++ct) {
                uint colc = (uint)(w * 64 + ct * 16 + lrow);
                float v = (acc[rt][ct][r] - mu) * rs * g1c[ct] + be1c[ct];
                v = v >= 0.0f ? v : ap * v;
                uint idx = ((row << 8) + colc) ^ ((row & 7u) << 3);
                hbuf[idx] = f32_to_bf16(v);
            }
        }
    }
    __syncthreads();

    // ---- Phase 4: GEMM2 — wave w owns cols [w*32, w*32+32) ---------------
    f32x4 acc2[4][2];
#pragma unroll
    for (int i = 0; i < 4; ++i)
#pragma unroll
        for (int j = 0; j < 2; ++j) acc2[i][j] = (f32x4)(0.0f);

#pragma unroll
    for (int ks = 0; ks < 8; ++ks) {
        short8 a[4];
#pragma unroll
        for (int rt = 0; rt < 4; ++rt) {
            uint row = (uint)(rt * 16 + lrow);
            uint idx = ((row << 8) + (uint)(ks * 32 + lk * 8)) ^ ((row & 7u) << 3);
            a[rt] = *(const short8*)&hbuf[idx];
        }
#pragma unroll
        for (int ct = 0; ct < 2; ++ct) {
            short8 b = *(const short8*)&W2p[(size_t)(((w * 2 + ct) * 8 + ks) * 64 + l) * 8];
#pragma unroll
            for (int rt = 0; rt < 4; ++rt)
                acc2[rt][ct] = __builtin_amdgcn_mfma_f32_16x16x32_bf16(
                    a[rt], b, acc2[rt][ct], 0, 0, 0);
        }
    }

    float b2c[2];
#pragma unroll
    for (int ct = 0; ct < 2; ++ct) b2c[ct] = b2[w * 32 + ct * 16 + lrow];

#pragma unroll
    for (int rt = 0; rt < 4; ++rt)
#pragma unroll
        for (int ct = 0; ct < 2; ++ct)
#pragma unroll
            for (int r = 0; r < 4; ++r) {
                int row = row0 + rt * 16 + lk * 4 + r;
                if (row < NNODES)
                    out[(size_t)row * HDIM + w * 32 + ct * 16 + lrow] =
                        acc2[rt][ct][r] + b2c[ct];
            }
}

// ---------------------------------------------------------------------------
extern "C" void kernel_launch(void* const* d_in, const int* in_sizes, int n_in,
                              void* d_out, int out_size, void* d_ws, size_t ws_size,
                              hipStream_t stream)
{
    const float* x         = (const float*)d_in[0];
    const int*   ei        = (const int*)  d_in[1];
    const float* edge_attr = (const float*)d_in[2];
    const float* W1        = (const float*)d_in[3];
    const float* b1        = (const float*)d_in[4];
    const float* gamma     = (const float*)d_in[5];
    const float* beta      = (const float*)d_in[6];
    const float* prelu_a   = (const float*)d_in[7];
    const float* W2        = (const float*)d_in[8];
    const float* b2        = (const float*)d_in[9];
    float*       out       = (float*)d_out;

    int* deg    = (int*)d_ws;            // [NNODES]
    int* excl   = deg + NNODES;          // [NNODES]
    int* bsum   = excl + NNODES;         // [512]
    int* off    = bsum + 512;            // [NNODES]
    int* cursor = off + NNODES;          // [NNODES]
    int* eid    = cursor + NNODES;       // [NEDGES]
    ushort* W1p = (ushort*)(eid + NEDGES);      // 16*8*64*8 elems (128 KB)
    ushort* W2p = W1p + 16 * 8 * 64 * 8;        //  8*8*64*8 elems (64 KB)
    ushort* agg = W2p + 8 * 8 * 64 * 8;         // [NNODES*HDIM] bf16 (25.6 MB)

    const int* colp = ei + NEDGES;       // edge_index[1]

    zero_deg<<<NB_SCAN, 256, 0, stream>>>(deg);
    deg_count<<<(NEDGES + 255) / 256, 256, 0, stream>>>(colp, deg);
    scan1<<<NB_SCAN, 256, 0, stream>>>(deg, excl, bsum);
    scan2<<<1, 512, 0, stream>>>(bsum);
    scan3<<<NB_SCAN, 256, 0, stream>>>(excl, bsum, off, cursor);
    fill_eid<<<(NEDGES + 255) / 256, 256, 0, stream>>>(colp, cursor, eid);

    gather_mean<<<(NNODES * 64 + 255) / 256, 256, 0, stream>>>(
        edge_attr, off, deg, eid, agg);

    pack_both<<<48, 256, 0, stream>>>(W1, W2, W1p, W2p);

    fused_mfma<<<(NNODES + 63) / 64, 256, 0, stream>>>(
        x, agg, W1p, b1, gamma, beta, prelu_a, W2p, b2, out);
}

// Round 9
// 216.458 us; speedup vs baseline: 3.1739x; 1.2959x over previous
//
#include <hip/hip_runtime.h>

#define NNODES 100000
#define NPAD   100032   // NNODES rounded up to 64 (fused tile rows)
#define NEDGES 600000
#define HDIM   128
#define H2     256
#define NB_SCAN 391   // ceil(NNODES/256)

typedef __attribute__((ext_vector_type(8))) short short8;
typedef __attribute__((ext_vector_type(4))) float f32x4;
typedef __attribute__((ext_vector_type(2))) float f32x2;

static __device__ __forceinline__ ushort f32_to_bf16(float f) {
    union { float f; uint u; } c; c.f = f;
    uint u = c.u;
    return (ushort)((u + 0x7fffu + ((u >> 16) & 1u)) >> 16);
}

// ---------------------------------------------------------------------------
// Zero the degree array.
// ---------------------------------------------------------------------------
__global__ __launch_bounds__(256) void zero_deg(int* __restrict__ deg)
{
    int i = blockIdx.x * 256 + threadIdx.x;
    if (i < NNODES) deg[i] = 0;
}

// ---------------------------------------------------------------------------
// CSR build: histogram -> 3-stage exclusive scan -> bucket fill -> sort
// ---------------------------------------------------------------------------
__global__ __launch_bounds__(256) void deg_count(
    const int* __restrict__ col, int* __restrict__ deg)
{
    int e = blockIdx.x * 256 + threadIdx.x;
    if (e < NEDGES) atomicAdd(&deg[col[e]], 1);
}

__global__ __launch_bounds__(256) void scan1(
    const int* __restrict__ deg, int* __restrict__ excl, int* __restrict__ bsum)
{
    __shared__ int s[256];
    int tid = threadIdx.x;
    int i = blockIdx.x * 256 + tid;
    int v = (i < NNODES) ? deg[i] : 0;
    s[tid] = v;
    __syncthreads();
    for (int off = 1; off < 256; off <<= 1) {
        int tv = (tid >= off) ? s[tid - off] : 0;
        __syncthreads();
        s[tid] += tv;
        __syncthreads();
    }
    if (i < NNODES) excl[i] = s[tid] - v;
    if (tid == 255) bsum[blockIdx.x] = s[255];
}

__global__ __launch_bounds__(512) void scan2(int* __restrict__ bsum)
{
    __shared__ int s[512];
    int t = threadIdx.x;
    int v = (t < NB_SCAN) ? bsum[t] : 0;
    s[t] = v;
    __syncthreads();
    for (int off = 1; off < 512; off <<= 1) {
        int u = (t >= off) ? s[t - off] : 0;
        __syncthreads();
        s[t] += u;
        __syncthreads();
    }
    if (t < NB_SCAN) bsum[t] = s[t] - v;   // exclusive block offsets
}

__global__ __launch_bounds__(256) void scan3(
    const int* __restrict__ excl, const int* __restrict__ bsum,
    int* __restrict__ off, int* __restrict__ cursor)
{
    int i = blockIdx.x * 256 + threadIdx.x;
    if (i < NNODES) {
        int o = excl[i] + bsum[blockIdx.x];
        off[i] = o;
        cursor[i] = o;
    }
}

__global__ __launch_bounds__(256) void fill_eid(
    const int* __restrict__ col, int* __restrict__ cursor, int* __restrict__ eid)
{
    int e = blockIdx.x * 256 + threadIdx.x;
    if (e < NEDGES) {
        int p = atomicAdd(&cursor[col[e]], 1);
        eid[p] = e;
    }
}

// Canonicalize intra-segment order (atomic cursor placement varies per call).
__global__ __launch_bounds__(256) void sort_eid(
    const int* __restrict__ off, const int* __restrict__ deg,
    int* __restrict__ eid)
{
    int n = blockIdx.x * 256 + threadIdx.x;
    if (n >= NNODES) return;
    int o = off[n], d = deg[n];
    for (int i = 1; i < d; ++i) {
        int v = eid[o + i];
        int j = i - 1;
        while (j >= 0 && eid[o + j] > v) { eid[o + j + 1] = eid[o + j]; --j; }
        eid[o + j + 1] = v;
    }
}

// ---------------------------------------------------------------------------
// Gather-mean + x-convert: ONE 64-lane WAVE per node. Writes hin[node][256]
// bf16 with the LDS XOR swizzle baked into the global layout
// (ushort idx ^= (node&7)<<3). Rows [NNODES, NPAD) are ZEROED so the fused
// kernel never reads unwritten workspace (determinism across poisons).
// ---------------------------------------------------------------------------
__global__ __launch_bounds__(256) void gather_mean(
    const float* __restrict__ x,
    const float* __restrict__ edge_attr,
    const int*   __restrict__ off,
    const int*   __restrict__ deg,
    const int*   __restrict__ eid,
    ushort*      __restrict__ hin)
{
    int wid = (blockIdx.x * 256 + threadIdx.x) >> 6;   // wave id = node
    if (wid >= NPAD) return;
    const int l  = threadIdx.x & 63;
    const int c2 = l * 2;
    const uint sw = ((uint)wid & 7u) << 3;

    if (wid >= NNODES) {                // zero pad rows
        ushort2 z = {0, 0};
        *(ushort2*)&hin[(size_t)wid * H2 + ((uint)c2 ^ sw)] = z;
        *(ushort2*)&hin[(size_t)wid * H2 + ((uint)(HDIM + c2) ^ sw)] = z;
        return;
    }

    // x half -> cols [0,128)
    f32x2 xv = __builtin_nontemporal_load(
        (const f32x2*)&x[(size_t)wid * HDIM + c2]);
    ushort2 hx;
    hx.x = f32_to_bf16(xv.x);
    hx.y = f32_to_bf16(xv.y);
    *(ushort2*)&hin[(size_t)wid * H2 + ((uint)c2 ^ sw)] = hx;

    // agg half -> cols [128,256)
    const int o  = __builtin_amdgcn_readfirstlane(off[wid]);
    const int dg = __builtin_amdgcn_readfirstlane(deg[wid]);

    f32x2 av = {0.f, 0.f};
    int p = 0;
    for (; p + 4 <= dg; p += 4) {
        int e0 = __builtin_amdgcn_readfirstlane(eid[o + p + 0]);
        int e1 = __builtin_amdgcn_readfirstlane(eid[o + p + 1]);
        int e2 = __builtin_amdgcn_readfirstlane(eid[o + p + 2]);
        int e3 = __builtin_amdgcn_readfirstlane(eid[o + p + 3]);
        f32x2 v0 = __builtin_nontemporal_load(
            (const f32x2*)&edge_attr[(size_t)e0 * HDIM + c2]);
        f32x2 v1 = __builtin_nontemporal_load(
            (const f32x2*)&edge_attr[(size_t)e1 * HDIM + c2]);
        f32x2 v2 = __builtin_nontemporal_load(
            (const f32x2*)&edge_attr[(size_t)e2 * HDIM + c2]);
        f32x2 v3 = __builtin_nontemporal_load(
            (const f32x2*)&edge_attr[(size_t)e3 * HDIM + c2]);
        av += ((v0 + v1) + (v2 + v3));
    }
    for (; p < dg; ++p) {
        int e0 = __builtin_amdgcn_readfirstlane(eid[o + p]);
        f32x2 v0 = __builtin_nontemporal_load(
            (const f32x2*)&edge_attr[(size_t)e0 * HDIM + c2]);
        av += v0;
    }
    float inv = 1.0f / fmaxf((float)dg, 1.0f);
    ushort2 ha;
    ha.x = f32_to_bf16(av.x * inv);
    ha.y = f32_to_bf16(av.y * inv);
    *(ushort2*)&hin[(size_t)wid * H2 + ((uint)(HDIM + c2) ^ sw)] = ha;
}

// ---------------------------------------------------------------------------
// Pack both weight matrices in ONE dispatch (bf16 MFMA B-frag order).
// ---------------------------------------------------------------------------
__device__ __forceinline__ void pack_one(
    const float* __restrict__ W, ushort* __restrict__ Wp, int ncols, int id)
{
    int l  = id & 63;
    int ks = (id >> 6) & 7;
    int nt = id >> 9;
    int colc = nt * 16 + (l & 15);
    int kb   = ks * 32 + (l >> 4) * 8;
    short8 v;
#pragma unroll
    for (int j = 0; j < 8; ++j)
        v[j] = (short)f32_to_bf16(W[(size_t)(kb + j) * ncols + colc]);
    *(short8*)&Wp[(size_t)id * 8] = v;
}

__global__ __launch_bounds__(256) void pack_both(
    const float* __restrict__ W1, const float* __restrict__ W2,
    ushort* __restrict__ W1p, ushort* __restrict__ W2p)
{
    int id = blockIdx.x * 256 + threadIdx.x;
    if (id < 16 * 8 * 64)            pack_one(W1, W1p, H2,   id);
    else if (id < 24 * 8 * 64)       pack_one(W2, W2p, HDIM, id - 16 * 8 * 64);
}

// ---------------------------------------------------------------------------
// Fused: hin tile (register staging, pre-swizzled) -> GEMM1 -> LN -> PReLU
//        -> GEMM2 -> out.  64 rows/block, 512 threads (8 waves).
// ---------------------------------------------------------------------------
__global__ __launch_bounds__(512, 4) void fused_mfma(
    const ushort* __restrict__ hin,
    const ushort* __restrict__ W1p,
    const float*  __restrict__ b1,
    const float*  __restrict__ gamma,
    const float*  __restrict__ beta,
    const float*  __restrict__ prelu_a,
    const ushort* __restrict__ W2p,
    const float*  __restrict__ b2,
    float*        __restrict__ out)
{
    __shared__ ushort hbuf[64 * H2];     // 32 KB bf16 tile (h_in, then h_mid)
    __shared__ float red_s[8][64];
    __shared__ float red_q[8][64];
    __shared__ float mu_l[64];
    __shared__ float rs_l[64];

    const int t = threadIdx.x;           // 0..511
    const int w = t >> 6;                // wave 0..7
    const int l = t & 63;
    const int lrow = l & 15;
    const int lk   = l >> 4;
    const int row0 = blockIdx.x * 64;

    // ---- Phase 1: register-staged copy of the pre-swizzled 32 KB tile ----
    {
        const ushort* hrow = hin + (size_t)row0 * H2;
#pragma unroll
        for (int it = 0; it < 4; ++it) {
            int flat = it * 512 + t;     // 16B chunk id, 2048 chunks total
            short8 v = *(const short8*)&hrow[flat * 8];
            *(short8*)&hbuf[flat * 8] = v;
        }
    }
    __syncthreads();

    // ---- Phase 2: GEMM1 — wave w owns cols [w*32, w*32+32) ---------------
    f32x4 acc[4][2];
#pragma unroll
    for (int i = 0; i < 4; ++i)
#pragma unroll
        for (int j = 0; j < 2; ++j) acc[i][j] = (f32x4)(0.0f);

#pragma unroll
    for (int ks = 0; ks < 8; ++ks) {
        short8 a[4];
#pragma unroll
        for (int rt = 0; rt < 4; ++rt) {
            uint row = (uint)(rt * 16 + lrow);
            uint idx = ((row << 8) + (uint)(ks * 32 + lk * 8)) ^ ((row & 7u) << 3);
            a[rt] = *(const short8*)&hbuf[idx];
        }
#pragma unroll
        for (int ct = 0; ct < 2; ++ct) {
            short8 b = *(const short8*)&W1p[(size_t)(((w * 2 + ct) * 8 + ks) * 64 + l) * 8];
#pragma unroll
            for (int rt = 0; rt < 4; ++rt)
                acc[rt][ct] = __builtin_amdgcn_mfma_f32_16x16x32_bf16(
                    a[rt], b, acc[rt][ct], 0, 0, 0);
        }
    }

    // ---- Phase 3: +bias, LN stats ----------------------------------------
    float b1c[2], g1c[2], be1c[2];
#pragma unroll
    for (int ct = 0; ct < 2; ++ct) {
        int colc = w * 32 + ct * 16 + lrow;
        b1c[ct] = b1[colc]; g1c[ct] = gamma[colc]; be1c[ct] = beta[colc];
    }
#pragma unroll
    for (int rt = 0; rt < 4; ++rt)
#pragma unroll
        for (int ct = 0; ct < 2; ++ct)
#pragma unroll
            for (int r = 0; r < 4; ++r) acc[rt][ct][r] += b1c[ct];

#pragma unroll
    for (int rt = 0; rt < 4; ++rt) {
        float s[4], qq[4];
#pragma unroll
        for (int r = 0; r < 4; ++r) {
            float v0 = acc[rt][0][r], v1 = acc[rt][1][r];
            s[r]  = v0 + v1;
            qq[r] = v0 * v0 + v1 * v1;
        }
#pragma unroll
        for (int off2 = 1; off2 < 16; off2 <<= 1) {
#pragma unroll
            for (int r = 0; r < 4; ++r) {
                s[r]  += __shfl_xor(s[r],  off2, 64);
                qq[r] += __shfl_xor(qq[r], off2, 64);
            }
        }
        if (lrow == 0) {
#pragma unroll
            for (int r = 0; r < 4; ++r) {
                int row = rt * 16 + lk * 4 + r;
                red_s[w][row] = s[r];
                red_q[w][row] = qq[r];
            }
        }
    }
    __syncthreads();
    if (t < 64) {
        float s = 0.f, qq = 0.f;
#pragma unroll
        for (int ww = 0; ww < 8; ++ww) { s += red_s[ww][t]; qq += red_q[ww][t]; }
        float mu  = s * (1.0f / H2);
        float var = qq * (1.0f / H2) - mu * mu;
        mu_l[t] = mu;
        rs_l[t] = rsqrtf(var + 1e-5f);
    }
    const float ap = prelu_a[0];
    __syncthreads();

    // ---- Phase 3b: normalize + PReLU -> h_mid bf16 (same LDS) ------------
#pragma unroll
    for (int rt = 0; rt < 4; ++rt) {
#pragma unroll
        for (int r = 0; r < 4; ++r) {
            uint row = (uint)(rt * 16 + lk * 4 + r);
            float mu = mu_l[row], rs = rs_l[row];
#pragma unroll
            for (int ct = 0; ct < 2; ++ct) {
                uint colc = (uint)(w * 32 + ct * 16 + lrow);
                float v = (acc[rt][ct][r] - mu) * rs * g1c[ct] + be1c[ct];
                v = v >= 0.0f ? v : ap * v;
                uint idx = ((row << 8) + colc) ^ ((row & 7u) << 3);
                hbuf[idx] = f32_to_bf16(v);
            }
        }
    }
    __syncthreads();

    // ---- Phase 4: GEMM2 — wave w owns cols [w*16, w*16+16) ---------------
    f32x4 acc2[4];
#pragma unroll
    for (int i = 0; i < 4; ++i) acc2[i] = (f32x4)(0.0f);

#pragma unroll
    for (int ks = 0; ks < 8; ++ks) {
        short8 a[4];
#pragma unroll
        for (int rt = 0; rt < 4; ++rt) {
            uint row = (uint)(rt * 16 + lrow);
            uint idx = ((row << 8) + (uint)(ks * 32 + lk * 8)) ^ ((row & 7u) << 3);
            a[rt] = *(const short8*)&hbuf[idx];
        }
        short8 b = *(const short8*)&W2p[(size_t)((w * 8 + ks) * 64 + l) * 8];
#pragma unroll
        for (int rt = 0; rt < 4; ++rt)
            acc2[rt] = __builtin_amdgcn_mfma_f32_16x16x32_bf16(
                a[rt], b, acc2[rt], 0, 0, 0);
    }

    float b2c = b2[w * 16 + lrow];
#pragma unroll
    for (int rt = 0; rt < 4; ++rt)
#pragma unroll
        for (int r = 0; r < 4; ++r) {
            int row = row0 + rt * 16 + lk * 4 + r;
            if (row < NNODES)
                out[(size_t)row * HDIM + w * 16 + lrow] = acc2[rt][r] + b2c;
        }
}

// ---------------------------------------------------------------------------
extern "C" void kernel_launch(void* const* d_in, const int* in_sizes, int n_in,
                              void* d_out, int out_size, void* d_ws, size_t ws_size,
                              hipStream_t stream)
{
    const float* x         = (const float*)d_in[0];
    const int*   ei        = (const int*)  d_in[1];
    const float* edge_attr = (const float*)d_in[2];
    const float* W1        = (const float*)d_in[3];
    const float* b1        = (const float*)d_in[4];
    const float* gamma     = (const float*)d_in[5];
    const float* beta      = (const float*)d_in[6];
    const float* prelu_a   = (const float*)d_in[7];
    const float* W2        = (const float*)d_in[8];
    const float* b2        = (const float*)d_in[9];
    float*       out       = (float*)d_out;

    int* deg    = (int*)d_ws;            // [NNODES]
    int* excl   = deg + NNODES;          // [NNODES]
    int* bsum   = excl + NNODES;         // [512]
    int* off    = bsum + 512;            // [NNODES]
    int* cursor = off + NNODES;          // [NNODES]
    int* eid    = cursor + NNODES;       // [NEDGES]
    ushort* W1p = (ushort*)(eid + NEDGES);      // 16*8*64*8 elems (128 KB)
    ushort* W2p = W1p + 16 * 8 * 64 * 8;        //  8*8*64*8 elems (64 KB)
    ushort* hin = W2p + 8 * 8 * 64 * 8;         // [NPAD*256] bf16

    const int* colp = ei + NEDGES;       // edge_index[1]

    zero_deg<<<NB_SCAN, 256, 0, stream>>>(deg);
    deg_count<<<(NEDGES + 255) / 256, 256, 0, stream>>>(colp, deg);
    scan1<<<NB_SCAN, 256, 0, stream>>>(deg, excl, bsum);
    scan2<<<1, 512, 0, stream>>>(bsum);
    scan3<<<NB_SCAN, 256, 0, stream>>>(excl, bsum, off, cursor);
    fill_eid<<<(NEDGES + 255) / 256, 256, 0, stream>>>(colp, cursor, eid);
    sort_eid<<<NB_SCAN, 256, 0, stream>>>(off, deg, eid);

    gather_mean<<<(NPAD * 64) / 256, 256, 0, stream>>>(
        x, edge_attr, off, deg, eid, hin);

    pack_both<<<48, 256, 0, stream>>>(W1, W2, W1p, W2p);

    fused_mfma<<<NPAD / 64, 512, 0, stream>>>(
        hin, W1p, b1, gamma, beta, prelu_a, W2p, b2, out);
}